// Round 2
// baseline (857.221 us; speedup 1.0000x reference)
//
#include <hip/hip_runtime.h>

#define N_NODES 50000
#define N_EDGES 800000
#define IN_DIM 512
#define NEG_SLOPE 0.2f

// ---------------- fp32 tiled GEMM: C[M,N] = A[M,K] x B[K,N] ----------------
// 64x64 block tile, 16-deep K tile, 256 threads, 4x4 microtile per thread.
template <int K>
__global__ __launch_bounds__(256) void gemm_tiled(const float* __restrict__ A,
                                                  const float* __restrict__ B,
                                                  float* __restrict__ C, int M,
                                                  int N) {
  __shared__ float As[16][68];  // [k][m], stride 68 floats = 272B (16B aligned)
  __shared__ float Bs[16][68];  // [k][n]
  const int t = threadIdx.x;
  const int tx = t & 15, ty = t >> 4;
  const int m0 = blockIdx.y * 64, n0 = blockIdx.x * 64;
  float acc[4][4] = {};
  int arow = m0 + (t >> 2);
  if (arow >= M) arow = M - 1;  // clamp (stores are guarded)
  const int acol = (t & 3) * 4;
  const int brow = t >> 4;
  const int bcol = n0 + (t & 15) * 4;
  for (int k0 = 0; k0 < K; k0 += 16) {
    float4 av = *(const float4*)(A + (size_t)arow * K + k0 + acol);
    As[acol + 0][t >> 2] = av.x;
    As[acol + 1][t >> 2] = av.y;
    As[acol + 2][t >> 2] = av.z;
    As[acol + 3][t >> 2] = av.w;
    *(float4*)(&Bs[brow][(t & 15) * 4]) =
        *(const float4*)(B + (size_t)(k0 + brow) * N + bcol);
    __syncthreads();
#pragma unroll
    for (int k = 0; k < 16; k++) {
      float4 a4 = *(const float4*)(&As[k][ty * 4]);
      float4 b4 = *(const float4*)(&Bs[k][tx * 4]);
      float a[4] = {a4.x, a4.y, a4.z, a4.w};
      float b[4] = {b4.x, b4.y, b4.z, b4.w};
#pragma unroll
      for (int i = 0; i < 4; i++)
#pragma unroll
        for (int j = 0; j < 4; j++) acc[i][j] += a[i] * b[j];
    }
    __syncthreads();
  }
#pragma unroll
  for (int i = 0; i < 4; i++) {
    int row = m0 + ty * 4 + i;
    if (row < M) {
      float4 v = {acc[i][0], acc[i][1], acc[i][2], acc[i][3]};
      *(float4*)(C + (size_t)row * N + n0 + tx * 4) = v;
    }
  }
}

// ---------------- el/er reductions ----------------
// Layer 1: block = node, wave = head (4 waves). el[n,h] = sum_d f[n,h,d]*al[h,d]
__global__ __launch_bounds__(256) void elr1_kernel(
    const float* __restrict__ f1, const float* __restrict__ al,
    const float* __restrict__ ar, float* __restrict__ el,
    float* __restrict__ er) {
  int n = blockIdx.x;
  int t = threadIdx.x;
  int h = t >> 6, lane = t & 63;
  float v = f1[(size_t)n * 256 + t];
  float a = v * al[t];
  float b = v * ar[t];
  for (int off = 32; off; off >>= 1) {
    a += __shfl_down(a, off);
    b += __shfl_down(b, off);
  }
  if (lane == 0) {
    el[n * 4 + h] = a;
    er[n * 4 + h] = b;
  }
}

// Layer 2: 1 head of 64. block = 4 nodes (wave each).
__global__ __launch_bounds__(256) void elr2_kernel(
    const float* __restrict__ f2, const float* __restrict__ al,
    const float* __restrict__ ar, float* __restrict__ el,
    float* __restrict__ er) {
  int w = threadIdx.x >> 6, lane = threadIdx.x & 63;
  int n = blockIdx.x * 4 + w;
  if (n >= N_NODES) return;
  float v = f2[(size_t)n * 64 + lane];
  float a = v * al[lane], b = v * ar[lane];
  for (int off = 32; off; off >>= 1) {
    a += __shfl_down(a, off);
    b += __shfl_down(b, off);
  }
  if (lane == 0) {
    el[n] = a;
    er[n] = b;
  }
}

// ---------------- CSR build (bucket edges by dst) ----------------
__global__ void hist_kernel(const int* __restrict__ dst,
                            int* __restrict__ counts) {
  int e = blockIdx.x * blockDim.x + threadIdx.x;
  if (e < N_EDGES) atomicAdd(&counts[dst[e]], 1);
}

__global__ __launch_bounds__(1024) void scan_kernel(
    const int* __restrict__ counts, int* __restrict__ offsets) {
  __shared__ int sums[1024];
  const int n = N_NODES;
  int t = threadIdx.x;
  const int chunk = (n + 1023) / 1024;
  int lo = t * chunk, hi = min(lo + chunk, n);
  int s = 0;
  for (int i = lo; i < hi; i++) s += counts[i];
  sums[t] = s;
  __syncthreads();
  for (int off = 1; off < 1024; off <<= 1) {
    int v = (t >= off) ? sums[t - off] : 0;
    __syncthreads();
    sums[t] += v;
    __syncthreads();
  }
  int base = (t == 0) ? 0 : sums[t - 1];
  for (int i = lo; i < hi; i++) {
    offsets[i] = base;
    base += counts[i];
  }
  if (t == 1023) offsets[n] = sums[1023];
}

__global__ void scatter_kernel(const int* __restrict__ src,
                               const int* __restrict__ dst,
                               const int* __restrict__ offsets,
                               int* __restrict__ fill,
                               int* __restrict__ csr_src) {
  int e = blockIdx.x * blockDim.x + threadIdx.x;
  if (e < N_EDGES) {
    int d = dst[e];
    int pos = offsets[d] + atomicAdd(&fill[d], 1);
    csr_src[pos] = src[e];
  }
}

// ---------------- softmax max/denominator (online), layer 1 ----------------
// one wave per node, 4 nodes per block; lanes stride over in-edges.
__global__ __launch_bounds__(256) void mden1_kernel(
    const int* __restrict__ offsets, const int* __restrict__ csr_src,
    const float* __restrict__ el, const float* __restrict__ er,
    float* __restrict__ mout, float* __restrict__ dout) {
  int w = threadIdx.x >> 6, lane = threadIdx.x & 63;
  int n = blockIdx.x * 4 + w;
  if (n >= N_NODES) return;
  int off0 = offsets[n], deg = offsets[n + 1] - off0;
  float4 erv = ((const float4*)er)[n];
  float er4[4] = {erv.x, erv.y, erv.z, erv.w};
  float m[4] = {-1e30f, -1e30f, -1e30f, -1e30f};
  float l[4] = {0.f, 0.f, 0.f, 0.f};
  for (int i = lane; i < deg; i += 64) {
    int s = csr_src[off0 + i];
    float4 elv = ((const float4*)el)[s];
    float e4[4] = {elv.x, elv.y, elv.z, elv.w};
#pragma unroll
    for (int h = 0; h < 4; h++) {
      float v = e4[h] + er4[h];
      v = v > 0.f ? v : NEG_SLOPE * v;
      float nm = fmaxf(m[h], v);
      l[h] = l[h] * __expf(m[h] - nm) + __expf(v - nm);
      m[h] = nm;
    }
  }
  for (int d = 32; d; d >>= 1) {
#pragma unroll
    for (int h = 0; h < 4; h++) {
      float mo = __shfl_down(m[h], d);
      float lo = __shfl_down(l[h], d);
      float nm = fmaxf(m[h], mo);
      l[h] = l[h] * __expf(m[h] - nm) + lo * __expf(mo - nm);
      m[h] = nm;
    }
  }
  if (lane == 0) {
#pragma unroll
    for (int h = 0; h < 4; h++) {
      mout[n * 4 + h] = m[h];
      dout[n * 4 + h] = l[h];
    }
  }
}

// layer 2 (1 head)
__global__ __launch_bounds__(256) void mden2_kernel(
    const int* __restrict__ offsets, const int* __restrict__ csr_src,
    const float* __restrict__ el, const float* __restrict__ er,
    float* __restrict__ mout, float* __restrict__ dout) {
  int w = threadIdx.x >> 6, lane = threadIdx.x & 63;
  int n = blockIdx.x * 4 + w;
  if (n >= N_NODES) return;
  int off0 = offsets[n], deg = offsets[n + 1] - off0;
  float ern = er[n];
  float m = -1e30f, l = 0.f;
  for (int i = lane; i < deg; i += 64) {
    int s = csr_src[off0 + i];
    float v = el[s] + ern;
    v = v > 0.f ? v : NEG_SLOPE * v;
    float nm = fmaxf(m, v);
    l = l * __expf(m - nm) + __expf(v - nm);
    m = nm;
  }
  for (int d = 32; d; d >>= 1) {
    float mo = __shfl_down(m, d);
    float lo = __shfl_down(l, d);
    float nm = fmaxf(m, mo);
    l = l * __expf(m - nm) + lo * __expf(mo - nm);
    m = nm;
  }
  if (lane == 0) {
    mout[n] = m;
    dout[n] = l;
  }
}

// ---------------- aggregation layer 1: block per node, thread = (h,d) -------
// fused: out = sum_e a*f[src] ; h1 = elu(out + bias)
__global__ __launch_bounds__(256) void agg1_kernel(
    const int* __restrict__ offsets, const int* __restrict__ csr_src,
    const float* __restrict__ el, const float* __restrict__ er,
    const float* __restrict__ mm, const float* __restrict__ den,
    const float* __restrict__ f1, const float* __restrict__ bias,
    float* __restrict__ h1) {
  int n = blockIdx.x;
  int t = threadIdx.x, h = t >> 6;
  int off0 = offsets[n], deg = offsets[n + 1] - off0;
  float erh = er[n * 4 + h];
  float mh = mm[n * 4 + h];
  float invd = 1.0f / den[n * 4 + h];  // deg==0: inf, never used
  float acc = 0.f;
  for (int i = 0; i < deg; i++) {
    int s = csr_src[off0 + i];
    float e = el[s * 4 + h] + erh;
    e = e > 0.f ? e : NEG_SLOPE * e;
    float a = __expf(e - mh) * invd;
    acc += a * f1[(size_t)s * 256 + t];
  }
  float r = acc + bias[t];
  h1[(size_t)n * 256 + t] = r > 0.f ? r : __expf(r) - 1.0f;  // ELU fused
}

// aggregation layer 2: wave per node, 4 nodes per block; d = lane.
__global__ __launch_bounds__(256) void agg2_kernel(
    const int* __restrict__ offsets, const int* __restrict__ csr_src,
    const float* __restrict__ el, const float* __restrict__ er,
    const float* __restrict__ mm, const float* __restrict__ den,
    const float* __restrict__ f2, const float* __restrict__ bias,
    float* __restrict__ out) {
  int w = threadIdx.x >> 6, lane = threadIdx.x & 63;
  int n = blockIdx.x * 4 + w;
  if (n >= N_NODES) return;
  int off0 = offsets[n], deg = offsets[n + 1] - off0;
  float ern = er[n], mn = mm[n];
  float invd = 1.0f / den[n];
  float acc = 0.f;
  for (int i = 0; i < deg; i++) {
    int s = csr_src[off0 + i];
    float e = el[s] + ern;
    e = e > 0.f ? e : NEG_SLOPE * e;
    float a = __expf(e - mn) * invd;
    acc += a * f2[(size_t)s * 64 + lane];
  }
  out[(size_t)n * 64 + lane] = acc + bias[lane];
}

extern "C" void kernel_launch(void* const* d_in, const int* in_sizes, int n_in,
                              void* d_out, int out_size, void* d_ws,
                              size_t ws_size, hipStream_t stream) {
  const float* features = (const float*)d_in[0];
  const float* W1 = (const float*)d_in[1];
  const float* al1 = (const float*)d_in[2];
  const float* ar1 = (const float*)d_in[3];
  const float* b1 = (const float*)d_in[4];
  const float* W2 = (const float*)d_in[5];
  const float* al2 = (const float*)d_in[6];
  const float* ar2 = (const float*)d_in[7];
  const float* b2 = (const float*)d_in[8];
  const int* src = (const int*)d_in[9];
  const int* dst = (const int*)d_in[10];
  float* out = (float*)d_out;

  // workspace layout (fp32 unless noted); f2 aliases f1 (f1 dead after agg1)
  float* f1 = (float*)d_ws;                    // N*256 = 51.2 MB
  float* h1 = f1 + (size_t)N_NODES * 256;      // N*256 = 51.2 MB
  float* f2 = f1;                              // N*64 (alias)
  float* el1 = h1 + (size_t)N_NODES * 256;     // N*4
  float* er1 = el1 + N_NODES * 4;              // N*4
  float* m1 = er1 + N_NODES * 4;               // N*4
  float* d1 = m1 + N_NODES * 4;                // N*4
  float* el2 = d1 + N_NODES * 4;               // N
  float* er2 = el2 + N_NODES;                  // N
  float* m2 = er2 + N_NODES;                   // N
  float* d2 = m2 + N_NODES;                    // N
  int* counts = (int*)(d2 + N_NODES);          // N
  int* offsets = counts + N_NODES;             // N+1
  int* fill = offsets + N_NODES + 1;           // N
  int* csr_src = fill + N_NODES;               // E

  // --- CSR build ---
  hipMemsetAsync(counts, 0, N_NODES * sizeof(int), stream);
  hipMemsetAsync(fill, 0, N_NODES * sizeof(int), stream);
  hist_kernel<<<(N_EDGES + 255) / 256, 256, 0, stream>>>(dst, counts);
  scan_kernel<<<1, 1024, 0, stream>>>(counts, offsets);
  scatter_kernel<<<(N_EDGES + 255) / 256, 256, 0, stream>>>(src, dst, offsets,
                                                            fill, csr_src);

  // --- layer 1 ---
  gemm_tiled<IN_DIM><<<dim3(4, (N_NODES + 63) / 64), 256, 0, stream>>>(
      features, W1, f1, N_NODES, 256);
  elr1_kernel<<<N_NODES, 256, 0, stream>>>(f1, al1, ar1, el1, er1);
  mden1_kernel<<<(N_NODES + 3) / 4, 256, 0, stream>>>(offsets, csr_src, el1,
                                                      er1, m1, d1);
  agg1_kernel<<<N_NODES, 256, 0, stream>>>(offsets, csr_src, el1, er1, m1, d1,
                                           f1, b1, h1);

  // --- layer 2 ---
  gemm_tiled<256><<<dim3(1, (N_NODES + 63) / 64), 256, 0, stream>>>(h1, W2, f2,
                                                                    N_NODES, 64);
  elr2_kernel<<<(N_NODES + 3) / 4, 256, 0, stream>>>(f2, al2, ar2, el2, er2);
  mden2_kernel<<<(N_NODES + 3) / 4, 256, 0, stream>>>(offsets, csr_src, el2,
                                                      er2, m2, d2);
  agg2_kernel<<<(N_NODES + 3) / 4, 256, 0, stream>>>(offsets, csr_src, el2, er2,
                                                     m2, d2, f2, b2, out);
}

// Round 3
// 730.374 us; speedup vs baseline: 1.1737x; 1.1737x over previous
//
#include <hip/hip_runtime.h>

#define N_NODES 50000
#define N_EDGES 800000
#define IN_DIM 512
#define NEG_SLOPE 0.2f

// ---------------- fp32 tiled GEMM: C[M,N] = A[M,K] x B[K,N] ----------------
// 64x64 block tile, 16-deep K tile, 256 threads, 4x4 microtile per thread.
// Software-pipelined: next K-tile prefetched into registers during compute.
template <int K>
__global__ __launch_bounds__(256) void gemm_tiled(const float* __restrict__ A,
                                                  const float* __restrict__ B,
                                                  float* __restrict__ C, int M,
                                                  int N) {
  __shared__ float As[16][68];  // [k][m], stride 68 floats = 272B (16B aligned)
  __shared__ float Bs[16][68];  // [k][n]
  const int t = threadIdx.x;
  const int tx = t & 15, ty = t >> 4;
  const int m0 = blockIdx.y * 64, n0 = blockIdx.x * 64;
  float acc[4][4] = {};
  int arow = m0 + (t >> 2);
  if (arow >= M) arow = M - 1;  // clamp (stores are guarded)
  const int acol = (t & 3) * 4;
  const int brow = t >> 4;
  const int bcol = n0 + (t & 15) * 4;
  float4 av = *(const float4*)(A + (size_t)arow * K + acol);
  float4 bv = *(const float4*)(B + (size_t)brow * N + bcol);
  for (int k0 = 0; k0 < K; k0 += 16) {
    As[acol + 0][t >> 2] = av.x;
    As[acol + 1][t >> 2] = av.y;
    As[acol + 2][t >> 2] = av.z;
    As[acol + 3][t >> 2] = av.w;
    *(float4*)(&Bs[brow][(t & 15) * 4]) = bv;
    __syncthreads();
    if (k0 + 16 < K) {
      av = *(const float4*)(A + (size_t)arow * K + k0 + 16 + acol);
      bv = *(const float4*)(B + (size_t)(k0 + 16 + brow) * N + bcol);
    }
#pragma unroll
    for (int k = 0; k < 16; k++) {
      float4 a4 = *(const float4*)(&As[k][ty * 4]);
      float4 b4 = *(const float4*)(&Bs[k][tx * 4]);
      float a[4] = {a4.x, a4.y, a4.z, a4.w};
      float b[4] = {b4.x, b4.y, b4.z, b4.w};
#pragma unroll
      for (int i = 0; i < 4; i++)
#pragma unroll
        for (int j = 0; j < 4; j++) acc[i][j] += a[i] * b[j];
    }
    __syncthreads();
  }
#pragma unroll
  for (int i = 0; i < 4; i++) {
    int row = m0 + ty * 4 + i;
    if (row < M) {
      float4 v = {acc[i][0], acc[i][1], acc[i][2], acc[i][3]};
      *(float4*)(C + (size_t)row * N + n0 + tx * 4) = v;
    }
  }
}

// ---------------- el/er reductions ----------------
__global__ __launch_bounds__(256) void elr1_kernel(
    const float* __restrict__ f1, const float* __restrict__ al,
    const float* __restrict__ ar, float* __restrict__ el,
    float* __restrict__ er) {
  int n = blockIdx.x;
  int t = threadIdx.x;
  int h = t >> 6, lane = t & 63;
  float v = f1[(size_t)n * 256 + t];
  float a = v * al[t];
  float b = v * ar[t];
  for (int off = 32; off; off >>= 1) {
    a += __shfl_down(a, off);
    b += __shfl_down(b, off);
  }
  if (lane == 0) {
    el[n * 4 + h] = a;
    er[n * 4 + h] = b;
  }
}

__global__ __launch_bounds__(256) void elr2_kernel(
    const float* __restrict__ f2, const float* __restrict__ al,
    const float* __restrict__ ar, float* __restrict__ el,
    float* __restrict__ er) {
  int w = threadIdx.x >> 6, lane = threadIdx.x & 63;
  int n = blockIdx.x * 4 + w;
  if (n >= N_NODES) return;
  float v = f2[(size_t)n * 64 + lane];
  float a = v * al[lane], b = v * ar[lane];
  for (int off = 32; off; off >>= 1) {
    a += __shfl_down(a, off);
    b += __shfl_down(b, off);
  }
  if (lane == 0) {
    el[n] = a;
    er[n] = b;
  }
}

// ---------------- CSR build (bucket edges by dst) ----------------
__global__ void hist_kernel(const int* __restrict__ dst,
                            int* __restrict__ counts) {
  int e = blockIdx.x * blockDim.x + threadIdx.x;
  if (e < N_EDGES) atomicAdd(&counts[dst[e]], 1);
}

__global__ __launch_bounds__(1024) void scan_kernel(
    const int* __restrict__ counts, int* __restrict__ offsets) {
  __shared__ int sums[1024];
  const int n = N_NODES;
  int t = threadIdx.x;
  const int chunk = (n + 1023) / 1024;
  int lo = t * chunk, hi = min(lo + chunk, n);
  int s = 0;
  for (int i = lo; i < hi; i++) s += counts[i];
  sums[t] = s;
  __syncthreads();
  for (int off = 1; off < 1024; off <<= 1) {
    int v = (t >= off) ? sums[t - off] : 0;
    __syncthreads();
    sums[t] += v;
    __syncthreads();
  }
  int base = (t == 0) ? 0 : sums[t - 1];
  for (int i = lo; i < hi; i++) {
    offsets[i] = base;
    base += counts[i];
  }
  if (t == 1023) offsets[n] = sums[1023];
}

__global__ void scatter_kernel(const int* __restrict__ src,
                               const int* __restrict__ dst,
                               const int* __restrict__ offsets,
                               int* __restrict__ fill,
                               int* __restrict__ csr_src) {
  int e = blockIdx.x * blockDim.x + threadIdx.x;
  if (e < N_EDGES) {
    int d = dst[e];
    int pos = offsets[d] + atomicAdd(&fill[d], 1);
    csr_src[pos] = src[e];
  }
}

// ---------------- softmax max/denominator (online) ----------------
__global__ __launch_bounds__(256) void mden1_kernel(
    const int* __restrict__ offsets, const int* __restrict__ csr_src,
    const float* __restrict__ el, const float* __restrict__ er,
    float* __restrict__ mout, float* __restrict__ dout) {
  int w = threadIdx.x >> 6, lane = threadIdx.x & 63;
  int n = blockIdx.x * 4 + w;
  if (n >= N_NODES) return;
  int off0 = offsets[n], deg = offsets[n + 1] - off0;
  float4 erv = ((const float4*)er)[n];
  float er4[4] = {erv.x, erv.y, erv.z, erv.w};
  float m[4] = {-1e30f, -1e30f, -1e30f, -1e30f};
  float l[4] = {0.f, 0.f, 0.f, 0.f};
  for (int i = lane; i < deg; i += 64) {
    int s = csr_src[off0 + i];
    float4 elv = ((const float4*)el)[s];
    float e4[4] = {elv.x, elv.y, elv.z, elv.w};
#pragma unroll
    for (int h = 0; h < 4; h++) {
      float v = e4[h] + er4[h];
      v = v > 0.f ? v : NEG_SLOPE * v;
      float nm = fmaxf(m[h], v);
      l[h] = l[h] * __expf(m[h] - nm) + __expf(v - nm);
      m[h] = nm;
    }
  }
  for (int d = 32; d; d >>= 1) {
#pragma unroll
    for (int h = 0; h < 4; h++) {
      float mo = __shfl_down(m[h], d);
      float lo = __shfl_down(l[h], d);
      float nm = fmaxf(m[h], mo);
      l[h] = l[h] * __expf(m[h] - nm) + lo * __expf(mo - nm);
      m[h] = nm;
    }
  }
  if (lane == 0) {
#pragma unroll
    for (int h = 0; h < 4; h++) {
      mout[n * 4 + h] = m[h];
      dout[n * 4 + h] = l[h];
    }
  }
}

__global__ __launch_bounds__(256) void mden2_kernel(
    const int* __restrict__ offsets, const int* __restrict__ csr_src,
    const float* __restrict__ el, const float* __restrict__ er,
    float* __restrict__ mout, float* __restrict__ dout) {
  int w = threadIdx.x >> 6, lane = threadIdx.x & 63;
  int n = blockIdx.x * 4 + w;
  if (n >= N_NODES) return;
  int off0 = offsets[n], deg = offsets[n + 1] - off0;
  float ern = er[n];
  float m = -1e30f, l = 0.f;
  for (int i = lane; i < deg; i += 64) {
    int s = csr_src[off0 + i];
    float v = el[s] + ern;
    v = v > 0.f ? v : NEG_SLOPE * v;
    float nm = fmaxf(m, v);
    l = l * __expf(m - nm) + __expf(v - nm);
    m = nm;
  }
  for (int d = 32; d; d >>= 1) {
    float mo = __shfl_down(m, d);
    float lo = __shfl_down(l, d);
    float nm = fmaxf(m, mo);
    l = l * __expf(m - nm) + lo * __expf(mo - nm);
    m = nm;
  }
  if (lane == 0) {
    mout[n] = m;
    dout[n] = l;
  }
}

// ---------------- aggregation layer 1 (restructured) ----------------
// block = node; 4 waves; wave w handles edges w, w+4, w+8, ...
// lane holds float4 of dims [4*lane, 4*lane+4) -> head h = lane>>4.
// 4 edges in flight x 16B/lane loads; LDS combine of the 4 wave partials.
__global__ __launch_bounds__(256) void agg1_kernel(
    const int* __restrict__ offsets, const int* __restrict__ csr_src,
    const float* __restrict__ el, const float* __restrict__ er,
    const float* __restrict__ mm, const float* __restrict__ den,
    const float* __restrict__ f1, const float* __restrict__ bias,
    float* __restrict__ h1) {
  __shared__ float red[3][256];
  int n = blockIdx.x;
  int t = threadIdx.x;
  int w = t >> 6, lane = t & 63;
  int h = lane >> 4;
  int off0 = offsets[n], deg = offsets[n + 1] - off0;
  float erh = er[n * 4 + h];
  float mh = mm[n * 4 + h];
  float invd = 1.0f / den[n * 4 + h];  // deg==0: inf, never multiplied
  float4 acc = {0.f, 0.f, 0.f, 0.f};
  for (int i = w; i < deg; i += 4) {
    int s = csr_src[off0 + i];
    float e = el[s * 4 + h] + erh;
    e = e > 0.f ? e : NEG_SLOPE * e;
    float a = __expf(e - mh) * invd;
    float4 v = *(const float4*)(f1 + (size_t)s * 256 + lane * 4);
    acc.x += a * v.x;
    acc.y += a * v.y;
    acc.z += a * v.z;
    acc.w += a * v.w;
  }
  if (w) *(float4*)(&red[w - 1][lane * 4]) = acc;
  __syncthreads();
  if (w == 0) {
    float4 r0 = *(float4*)(&red[0][lane * 4]);
    float4 r1 = *(float4*)(&red[1][lane * 4]);
    float4 r2 = *(float4*)(&red[2][lane * 4]);
    float4 b = ((const float4*)bias)[lane];
    float o[4] = {acc.x + r0.x + r1.x + r2.x + b.x,
                  acc.y + r0.y + r1.y + r2.y + b.y,
                  acc.z + r0.z + r1.z + r2.z + b.z,
                  acc.w + r0.w + r1.w + r2.w + b.w};
#pragma unroll
    for (int j = 0; j < 4; j++) o[j] = o[j] > 0.f ? o[j] : __expf(o[j]) - 1.0f;
    float4 ov = {o[0], o[1], o[2], o[3]};
    *(float4*)(h1 + (size_t)n * 256 + lane * 4) = ov;
  }
}

// ---------------- aggregation layer 2 (restructured) ----------------
// wave = node (4 nodes/block). lane: dimgroup = lane&15 (float4 of dims),
// eslot = lane>>4 (4 edges in flight). Butterfly-combine over eslots.
__global__ __launch_bounds__(256) void agg2_kernel(
    const int* __restrict__ offsets, const int* __restrict__ csr_src,
    const float* __restrict__ el, const float* __restrict__ er,
    const float* __restrict__ mm, const float* __restrict__ den,
    const float* __restrict__ f2, const float* __restrict__ bias,
    float* __restrict__ out) {
  int w = threadIdx.x >> 6, lane = threadIdx.x & 63;
  int n = blockIdx.x * 4 + w;
  if (n >= N_NODES) return;
  int dg = lane & 15, eslot = lane >> 4;
  int off0 = offsets[n], deg = offsets[n + 1] - off0;
  float ern = er[n], mn = mm[n];
  float invd = 1.0f / den[n];
  float4 acc = {0.f, 0.f, 0.f, 0.f};
  for (int i = eslot; i < deg; i += 4) {
    int s = csr_src[off0 + i];
    float e = el[s] + ern;
    e = e > 0.f ? e : NEG_SLOPE * e;
    float a = __expf(e - mn) * invd;
    float4 v = *(const float4*)(f2 + (size_t)s * 64 + dg * 4);
    acc.x += a * v.x;
    acc.y += a * v.y;
    acc.z += a * v.z;
    acc.w += a * v.w;
  }
#pragma unroll
  for (int off = 16; off < 64; off <<= 1) {
    acc.x += __shfl_xor(acc.x, off);
    acc.y += __shfl_xor(acc.y, off);
    acc.z += __shfl_xor(acc.z, off);
    acc.w += __shfl_xor(acc.w, off);
  }
  if (eslot == 0) {
    float4 b = ((const float4*)bias)[dg];
    float4 ov = {acc.x + b.x, acc.y + b.y, acc.z + b.z, acc.w + b.w};
    *(float4*)(out + (size_t)n * 64 + dg * 4) = ov;
  }
}

extern "C" void kernel_launch(void* const* d_in, const int* in_sizes, int n_in,
                              void* d_out, int out_size, void* d_ws,
                              size_t ws_size, hipStream_t stream) {
  const float* features = (const float*)d_in[0];
  const float* W1 = (const float*)d_in[1];
  const float* al1 = (const float*)d_in[2];
  const float* ar1 = (const float*)d_in[3];
  const float* b1 = (const float*)d_in[4];
  const float* W2 = (const float*)d_in[5];
  const float* al2 = (const float*)d_in[6];
  const float* ar2 = (const float*)d_in[7];
  const float* b2 = (const float*)d_in[8];
  const int* src = (const int*)d_in[9];
  const int* dst = (const int*)d_in[10];
  float* out = (float*)d_out;

  float* f1 = (float*)d_ws;                 // N*256
  float* h1 = f1 + (size_t)N_NODES * 256;   // N*256
  float* f2 = f1;                           // N*64 (alias; f1 dead after agg1)
  float* el1 = h1 + (size_t)N_NODES * 256;  // N*4
  float* er1 = el1 + N_NODES * 4;
  float* m1 = er1 + N_NODES * 4;
  float* d1 = m1 + N_NODES * 4;
  float* el2 = d1 + N_NODES * 4;  // N
  float* er2 = el2 + N_NODES;
  float* m2 = er2 + N_NODES;
  float* d2 = m2 + N_NODES;
  int* counts = (int*)(d2 + N_NODES);  // N
  int* offsets = counts + N_NODES;     // N+1
  int* fill = offsets + N_NODES + 1;   // N
  int* csr_src = fill + N_NODES;       // E

  // --- CSR build ---
  hipMemsetAsync(counts, 0, N_NODES * sizeof(int), stream);
  hipMemsetAsync(fill, 0, N_NODES * sizeof(int), stream);
  hist_kernel<<<(N_EDGES + 255) / 256, 256, 0, stream>>>(dst, counts);
  scan_kernel<<<1, 1024, 0, stream>>>(counts, offsets);
  scatter_kernel<<<(N_EDGES + 255) / 256, 256, 0, stream>>>(src, dst, offsets,
                                                            fill, csr_src);

  // --- layer 1 ---
  gemm_tiled<IN_DIM><<<dim3(4, (N_NODES + 63) / 64), 256, 0, stream>>>(
      features, W1, f1, N_NODES, 256);
  elr1_kernel<<<N_NODES, 256, 0, stream>>>(f1, al1, ar1, el1, er1);
  mden1_kernel<<<(N_NODES + 3) / 4, 256, 0, stream>>>(offsets, csr_src, el1,
                                                      er1, m1, d1);
  agg1_kernel<<<N_NODES, 256, 0, stream>>>(offsets, csr_src, el1, er1, m1, d1,
                                           f1, b1, h1);

  // --- layer 2 ---
  gemm_tiled<256><<<dim3(1, (N_NODES + 63) / 64), 256, 0, stream>>>(h1, W2, f2,
                                                                    N_NODES, 64);
  elr2_kernel<<<(N_NODES + 3) / 4, 256, 0, stream>>>(f2, al2, ar2, el2, er2);
  mden2_kernel<<<(N_NODES + 3) / 4, 256, 0, stream>>>(offsets, csr_src, el2,
                                                      er2, m2, d2);
  agg2_kernel<<<(N_NODES + 3) / 4, 256, 0, stream>>>(offsets, csr_src, el2, er2,
                                                     m2, d2, f2, b2, out);
}

// Round 4
// 586.367 us; speedup vs baseline: 1.4619x; 1.2456x over previous
//
#include <hip/hip_runtime.h>

#define N_NODES 50000
#define N_EDGES 800000
#define IN_DIM 512
#define NEG_SLOPE 0.2f

typedef short short8 __attribute__((ext_vector_type(8)));
typedef float f32x16 __attribute__((ext_vector_type(16)));

// ---------------- bf16 split helpers (RNE) ----------------
__device__ __forceinline__ unsigned bf16rne(float f) {
  union { float f; unsigned u; } v;
  v.f = f;
  return (v.u + 0x7FFFu + ((v.u >> 16) & 1u)) >> 16;
}
__device__ __forceinline__ float bf16tof(unsigned b) {
  union { unsigned u; float f; } v;
  v.u = b << 16;
  return v.f;
}
__device__ __forceinline__ void split8(float4 a, float4 b, short8& hi,
                                       short8& lo) {
  float v[8] = {a.x, a.y, a.z, a.w, b.x, b.y, b.z, b.w};
#pragma unroll
  for (int i = 0; i < 8; i++) {
    unsigned h = bf16rne(v[i]);
    hi[i] = (short)h;
    lo[i] = (short)bf16rne(v[i] - bf16tof(h));
  }
}

// ---------------- W pre-pack into MFMA B-fragment order ----------------
// B[k][n] -> frag: lane = (n&31)|(((k>>3)&1)<<5), 8 consecutive k per lane.
// Layout: [(ksub*(N/32) + nsub)*64 + lane]*8 + (k&7), hi/lo bf16 planes.
__global__ void pack_w(const float* __restrict__ W, short* __restrict__ Bhi,
                       short* __restrict__ Blo, int N) {
  int k = blockIdx.x, n = threadIdx.x;
  float w = W[(size_t)k * N + n];
  unsigned h = bf16rne(w);
  unsigned l = bf16rne(w - bf16tof(h));
  int ksub = k >> 4, kh = (k >> 3) & 1, j = k & 7;
  int nsub = n >> 5, lane2 = (n & 31) | (kh << 5);
  size_t off = (((size_t)ksub * (N >> 5) + nsub) * 64 + lane2) * 8 + j;
  Bhi[off] = (short)h;
  Blo[off] = (short)l;
}

// ---------------- split-bf16 MFMA GEMM, barrier-free ----------------
// C[M, NSUBS*32] = A[M,K] x B. Wave = 64x64 tile (2x2 of 32x32 MFMA).
// wid -> (mtile, ntile); NTILES = N/64. 3-term split: hi*hi + hi*lo + lo*hi.
template <int K, int NSUBS, int NTILES>
__global__ __launch_bounds__(256) void gemm_mfma(const float* __restrict__ A,
                                                 const short* __restrict__ Bhi_,
                                                 const short* __restrict__ Blo_,
                                                 float* __restrict__ C, int M) {
  const int N = NSUBS * 32;
  int lane = threadIdx.x & 63;
  int wid = blockIdx.x * 4 + (threadIdx.x >> 6);
  int mtiles = (M + 63) >> 6;
  int mtile = wid / NTILES, ntile = wid % NTILES;
  if (mtile >= mtiles) return;
  int half = lane >> 5, l31 = lane & 31;
  int m0 = mtile * 64;
  int r0 = min(m0 + l31, M - 1);
  int r1 = min(m0 + 32 + l31, M - 1);
  const float* a0p = A + (size_t)r0 * K + half * 8;
  const float* a1p = A + (size_t)r1 * K + half * 8;
  const short8* bh = (const short8*)Bhi_;
  const short8* bl = (const short8*)Blo_;
  size_t bidx = (size_t)(ntile * 2) * 64 + lane;
  f32x16 acc00 = {}, acc01 = {}, acc10 = {}, acc11 = {};
#pragma unroll 2
  for (int ks = 0; ks < K / 16; ks++) {
    float4 x0 = *(const float4*)(a0p + ks * 16);
    float4 x1 = *(const float4*)(a0p + ks * 16 + 4);
    float4 y0 = *(const float4*)(a1p + ks * 16);
    float4 y1 = *(const float4*)(a1p + ks * 16 + 4);
    short8 a0h, a0l, a1h, a1l;
    split8(x0, x1, a0h, a0l);
    split8(y0, y1, a1h, a1l);
    size_t bb = bidx + (size_t)ks * NSUBS * 64;
    short8 b0h = bh[bb], b0l = bl[bb];
    short8 b1h = bh[bb + 64], b1l = bl[bb + 64];
    acc00 = __builtin_amdgcn_mfma_f32_32x32x16_bf16(a0h, b0h, acc00, 0, 0, 0);
    acc00 = __builtin_amdgcn_mfma_f32_32x32x16_bf16(a0h, b0l, acc00, 0, 0, 0);
    acc00 = __builtin_amdgcn_mfma_f32_32x32x16_bf16(a0l, b0h, acc00, 0, 0, 0);
    acc01 = __builtin_amdgcn_mfma_f32_32x32x16_bf16(a0h, b1h, acc01, 0, 0, 0);
    acc01 = __builtin_amdgcn_mfma_f32_32x32x16_bf16(a0h, b1l, acc01, 0, 0, 0);
    acc01 = __builtin_amdgcn_mfma_f32_32x32x16_bf16(a0l, b1h, acc01, 0, 0, 0);
    acc10 = __builtin_amdgcn_mfma_f32_32x32x16_bf16(a1h, b0h, acc10, 0, 0, 0);
    acc10 = __builtin_amdgcn_mfma_f32_32x32x16_bf16(a1h, b0l, acc10, 0, 0, 0);
    acc10 = __builtin_amdgcn_mfma_f32_32x32x16_bf16(a1l, b0h, acc10, 0, 0, 0);
    acc11 = __builtin_amdgcn_mfma_f32_32x32x16_bf16(a1h, b1h, acc11, 0, 0, 0);
    acc11 = __builtin_amdgcn_mfma_f32_32x32x16_bf16(a1h, b1l, acc11, 0, 0, 0);
    acc11 = __builtin_amdgcn_mfma_f32_32x32x16_bf16(a1l, b1h, acc11, 0, 0, 0);
  }
  // C/D layout (m74/m101 verified): col=lane&31, row=(r&3)+8*(r>>2)+4*half
  int colbase = ntile * 64 + l31;
#pragma unroll
  for (int r = 0; r < 16; r++) {
    int roff = (r & 3) + 8 * (r >> 2) + 4 * half;
    int row = m0 + roff;
    if (row < M) {
      C[(size_t)row * N + colbase] = acc00[r];
      C[(size_t)row * N + colbase + 32] = acc01[r];
    }
    if (row + 32 < M) {
      C[(size_t)(row + 32) * N + colbase] = acc10[r];
      C[(size_t)(row + 32) * N + colbase + 32] = acc11[r];
    }
  }
}

// ---------------- el/er reductions ----------------
__global__ __launch_bounds__(256) void elr1_kernel(
    const float* __restrict__ f1, const float* __restrict__ al,
    const float* __restrict__ ar, float* __restrict__ el,
    float* __restrict__ er) {
  int n = blockIdx.x;
  int t = threadIdx.x;
  int h = t >> 6, lane = t & 63;
  float v = f1[(size_t)n * 256 + t];
  float a = v * al[t];
  float b = v * ar[t];
  for (int off = 32; off; off >>= 1) {
    a += __shfl_down(a, off);
    b += __shfl_down(b, off);
  }
  if (lane == 0) {
    el[n * 4 + h] = a;
    er[n * 4 + h] = b;
  }
}

__global__ __launch_bounds__(256) void elr2_kernel(
    const float* __restrict__ f2, const float* __restrict__ al,
    const float* __restrict__ ar, float* __restrict__ el,
    float* __restrict__ er) {
  int w = threadIdx.x >> 6, lane = threadIdx.x & 63;
  int n = blockIdx.x * 4 + w;
  if (n >= N_NODES) return;
  float v = f2[(size_t)n * 64 + lane];
  float a = v * al[lane], b = v * ar[lane];
  for (int off = 32; off; off >>= 1) {
    a += __shfl_down(a, off);
    b += __shfl_down(b, off);
  }
  if (lane == 0) {
    el[n] = a;
    er[n] = b;
  }
}

// ---------------- CSR build ----------------
__global__ void hist_kernel(const int* __restrict__ dst,
                            int* __restrict__ counts) {
  int e = blockIdx.x * blockDim.x + threadIdx.x;
  if (e < N_EDGES) atomicAdd(&counts[dst[e]], 1);
}

#define NSCAN 196  // ceil(50000/256)
__global__ __launch_bounds__(256) void scan_part(const int* __restrict__ counts,
                                                 int* __restrict__ offsets,
                                                 int* __restrict__ bsums) {
  __shared__ int sh[256];
  int t = threadIdx.x;
  int i = blockIdx.x * 256 + t;
  int v = (i < N_NODES) ? counts[i] : 0;
  sh[t] = v;
  __syncthreads();
  for (int o = 1; o < 256; o <<= 1) {
    int x = (t >= o) ? sh[t - o] : 0;
    __syncthreads();
    sh[t] += x;
    __syncthreads();
  }
  if (i < N_NODES) offsets[i] = sh[t] - v;  // exclusive within block
  if (t == 255) bsums[blockIdx.x] = sh[255];
}
__global__ __launch_bounds__(256) void scan_top(int* __restrict__ bsums) {
  __shared__ int sh[256];
  int t = threadIdx.x;
  int v = (t < NSCAN) ? bsums[t] : 0;
  sh[t] = v;
  __syncthreads();
  for (int o = 1; o < 256; o <<= 1) {
    int x = (t >= o) ? sh[t - o] : 0;
    __syncthreads();
    sh[t] += x;
    __syncthreads();
  }
  if (t < NSCAN) bsums[t] = sh[t] - v;  // exclusive block bases
}
__global__ __launch_bounds__(256) void scan_add(int* __restrict__ offsets,
                                                const int* __restrict__ bsums) {
  int i = blockIdx.x * 256 + threadIdx.x;
  if (i < N_NODES) offsets[i] += bsums[blockIdx.x];
  if (i == 0) offsets[N_NODES] = N_EDGES;
}

__global__ void scatter_kernel(const int* __restrict__ src,
                               const int* __restrict__ dst,
                               const int* __restrict__ offsets,
                               int* __restrict__ fill,
                               int* __restrict__ csr_src) {
  int e = blockIdx.x * blockDim.x + threadIdx.x;
  if (e < N_EDGES) {
    int d = dst[e];
    int pos = offsets[d] + atomicAdd(&fill[d], 1);
    csr_src[pos] = src[e];
  }
}

// ---------------- softmax max/denominator (online) ----------------
__global__ __launch_bounds__(256) void mden1_kernel(
    const int* __restrict__ offsets, const int* __restrict__ csr_src,
    const float* __restrict__ el, const float* __restrict__ er,
    float* __restrict__ mout, float* __restrict__ dout) {
  int w = threadIdx.x >> 6, lane = threadIdx.x & 63;
  int n = blockIdx.x * 4 + w;
  if (n >= N_NODES) return;
  int off0 = offsets[n], deg = offsets[n + 1] - off0;
  float4 erv = ((const float4*)er)[n];
  float er4[4] = {erv.x, erv.y, erv.z, erv.w};
  float m[4] = {-1e30f, -1e30f, -1e30f, -1e30f};
  float l[4] = {0.f, 0.f, 0.f, 0.f};
  for (int i = lane; i < deg; i += 64) {
    int s = csr_src[off0 + i];
    float4 elv = ((const float4*)el)[s];
    float e4[4] = {elv.x, elv.y, elv.z, elv.w};
#pragma unroll
    for (int h = 0; h < 4; h++) {
      float v = e4[h] + er4[h];
      v = v > 0.f ? v : NEG_SLOPE * v;
      float nm = fmaxf(m[h], v);
      l[h] = l[h] * __expf(m[h] - nm) + __expf(v - nm);
      m[h] = nm;
    }
  }
  for (int d = 32; d; d >>= 1) {
#pragma unroll
    for (int h = 0; h < 4; h++) {
      float mo = __shfl_down(m[h], d);
      float lo = __shfl_down(l[h], d);
      float nm = fmaxf(m[h], mo);
      l[h] = l[h] * __expf(m[h] - nm) + lo * __expf(mo - nm);
      m[h] = nm;
    }
  }
  if (lane == 0) {
#pragma unroll
    for (int h = 0; h < 4; h++) {
      mout[n * 4 + h] = m[h];
      dout[n * 4 + h] = l[h];
    }
  }
}

__global__ __launch_bounds__(256) void mden2_kernel(
    const int* __restrict__ offsets, const int* __restrict__ csr_src,
    const float* __restrict__ el, const float* __restrict__ er,
    float* __restrict__ mout, float* __restrict__ dout) {
  int w = threadIdx.x >> 6, lane = threadIdx.x & 63;
  int n = blockIdx.x * 4 + w;
  if (n >= N_NODES) return;
  int off0 = offsets[n], deg = offsets[n + 1] - off0;
  float ern = er[n];
  float m = -1e30f, l = 0.f;
  for (int i = lane; i < deg; i += 64) {
    int s = csr_src[off0 + i];
    float v = el[s] + ern;
    v = v > 0.f ? v : NEG_SLOPE * v;
    float nm = fmaxf(m, v);
    l = l * __expf(m - nm) + __expf(v - nm);
    m = nm;
  }
  for (int d = 32; d; d >>= 1) {
    float mo = __shfl_down(m, d);
    float lo = __shfl_down(l, d);
    float nm = fmaxf(m, mo);
    l = l * __expf(m - nm) + lo * __expf(mo - nm);
    m = nm;
  }
  if (lane == 0) {
    mout[n] = m;
    dout[n] = l;
  }
}

// ---------------- aggregation layer 1 ----------------
__global__ __launch_bounds__(256) void agg1_kernel(
    const int* __restrict__ offsets, const int* __restrict__ csr_src,
    const float* __restrict__ el, const float* __restrict__ er,
    const float* __restrict__ mm, const float* __restrict__ den,
    const float* __restrict__ f1, const float* __restrict__ bias,
    float* __restrict__ h1) {
  __shared__ float red[3][256];
  int n = blockIdx.x;
  int t = threadIdx.x;
  int w = t >> 6, lane = t & 63;
  int h = lane >> 4;
  int off0 = offsets[n], deg = offsets[n + 1] - off0;
  float erh = er[n * 4 + h];
  float mh = mm[n * 4 + h];
  float invd = 1.0f / den[n * 4 + h];
  float4 acc = {0.f, 0.f, 0.f, 0.f};
  for (int i = w; i < deg; i += 4) {
    int s = csr_src[off0 + i];
    float e = el[s * 4 + h] + erh;
    e = e > 0.f ? e : NEG_SLOPE * e;
    float a = __expf(e - mh) * invd;
    float4 v = *(const float4*)(f1 + (size_t)s * 256 + lane * 4);
    acc.x += a * v.x;
    acc.y += a * v.y;
    acc.z += a * v.z;
    acc.w += a * v.w;
  }
  if (w) *(float4*)(&red[w - 1][lane * 4]) = acc;
  __syncthreads();
  if (w == 0) {
    float4 r0 = *(float4*)(&red[0][lane * 4]);
    float4 r1 = *(float4*)(&red[1][lane * 4]);
    float4 r2 = *(float4*)(&red[2][lane * 4]);
    float4 b = ((const float4*)bias)[lane];
    float o[4] = {acc.x + r0.x + r1.x + r2.x + b.x,
                  acc.y + r0.y + r1.y + r2.y + b.y,
                  acc.z + r0.z + r1.z + r2.z + b.z,
                  acc.w + r0.w + r1.w + r2.w + b.w};
#pragma unroll
    for (int j = 0; j < 4; j++) o[j] = o[j] > 0.f ? o[j] : __expf(o[j]) - 1.0f;
    float4 ov = {o[0], o[1], o[2], o[3]};
    *(float4*)(h1 + (size_t)n * 256 + lane * 4) = ov;
  }
}

// ---------------- aggregation layer 2 ----------------
__global__ __launch_bounds__(256) void agg2_kernel(
    const int* __restrict__ offsets, const int* __restrict__ csr_src,
    const float* __restrict__ el, const float* __restrict__ er,
    const float* __restrict__ mm, const float* __restrict__ den,
    const float* __restrict__ f2, const float* __restrict__ bias,
    float* __restrict__ out) {
  int w = threadIdx.x >> 6, lane = threadIdx.x & 63;
  int n = blockIdx.x * 4 + w;
  if (n >= N_NODES) return;
  int dg = lane & 15, eslot = lane >> 4;
  int off0 = offsets[n], deg = offsets[n + 1] - off0;
  float ern = er[n], mn = mm[n];
  float invd = 1.0f / den[n];
  float4 acc = {0.f, 0.f, 0.f, 0.f};
  for (int i = eslot; i < deg; i += 4) {
    int s = csr_src[off0 + i];
    float e = el[s] + ern;
    e = e > 0.f ? e : NEG_SLOPE * e;
    float a = __expf(e - mn) * invd;
    float4 v = *(const float4*)(f2 + (size_t)s * 64 + dg * 4);
    acc.x += a * v.x;
    acc.y += a * v.y;
    acc.z += a * v.z;
    acc.w += a * v.w;
  }
#pragma unroll
  for (int off = 16; off < 64; off <<= 1) {
    acc.x += __shfl_xor(acc.x, off);
    acc.y += __shfl_xor(acc.y, off);
    acc.z += __shfl_xor(acc.z, off);
    acc.w += __shfl_xor(acc.w, off);
  }
  if (eslot == 0) {
    float4 b = ((const float4*)bias)[dg];
    float4 ov = {acc.x + b.x, acc.y + b.y, acc.z + b.z, acc.w + b.w};
    *(float4*)(out + (size_t)n * 64 + dg * 4) = ov;
  }
}

extern "C" void kernel_launch(void* const* d_in, const int* in_sizes, int n_in,
                              void* d_out, int out_size, void* d_ws,
                              size_t ws_size, hipStream_t stream) {
  const float* features = (const float*)d_in[0];
  const float* W1 = (const float*)d_in[1];
  const float* al1 = (const float*)d_in[2];
  const float* ar1 = (const float*)d_in[3];
  const float* b1 = (const float*)d_in[4];
  const float* W2 = (const float*)d_in[5];
  const float* al2 = (const float*)d_in[6];
  const float* ar2 = (const float*)d_in[7];
  const float* b2 = (const float*)d_in[8];
  const int* src = (const int*)d_in[9];
  const int* dst = (const int*)d_in[10];
  float* out = (float*)d_out;

  float* f1 = (float*)d_ws;                 // N*256
  float* h1 = f1 + (size_t)N_NODES * 256;   // N*256
  float* f2 = f1;                           // N*64 (alias; f1 dead after agg1)
  float* el1 = h1 + (size_t)N_NODES * 256;  // N*4
  float* er1 = el1 + N_NODES * 4;
  float* m1 = er1 + N_NODES * 4;
  float* d1 = m1 + N_NODES * 4;
  float* el2 = d1 + N_NODES * 4;  // N
  float* er2 = el2 + N_NODES;
  float* m2 = er2 + N_NODES;
  float* d2 = m2 + N_NODES;
  int* counts = (int*)(d2 + N_NODES);  // N
  int* offsets = counts + N_NODES;     // N+1
  int* fill = offsets + N_NODES + 1;   // N
  int* csr_src = fill + N_NODES;       // E
  int* bsums = csr_src + N_EDGES;      // NSCAN

  // B-pack scratch: b1 packs live in d_out (dead until agg2);
  // b2 packs live in `fill` (dead after scatter).
  short* b1hi = (short*)d_out;          // 512*256 shorts
  short* b1lo = b1hi + 512 * 256;       // 512*256 shorts (total 524 KB << 12.8 MB)
  short* b2hi = (short*)fill;           // 256*64 shorts
  short* b2lo = b2hi + 256 * 64;        // (total 64 KB << 200 KB)

  // --- CSR build ---
  hipMemsetAsync(counts, 0, N_NODES * sizeof(int), stream);
  hipMemsetAsync(fill, 0, N_NODES * sizeof(int), stream);
  hist_kernel<<<(N_EDGES + 255) / 256, 256, 0, stream>>>(dst, counts);
  scan_part<<<NSCAN, 256, 0, stream>>>(counts, offsets, bsums);
  scan_top<<<1, 256, 0, stream>>>(bsums);
  scan_add<<<NSCAN, 256, 0, stream>>>(offsets, bsums);
  scatter_kernel<<<(N_EDGES + 255) / 256, 256, 0, stream>>>(src, dst, offsets,
                                                            fill, csr_src);

  // --- weight packing (after scatter: b2 reuses `fill`) ---
  pack_w<<<512, 256, 0, stream>>>(W1, b1hi, b1lo, 256);
  pack_w<<<256, 64, 0, stream>>>(W2, b2hi, b2lo, 64);

  // --- layer 1 ---
  gemm_mfma<IN_DIM, 8, 4><<<782, 256, 0, stream>>>(features, b1hi, b1lo, f1,
                                                   N_NODES);
  elr1_kernel<<<N_NODES, 256, 0, stream>>>(f1, al1, ar1, el1, er1);
  mden1_kernel<<<(N_NODES + 3) / 4, 256, 0, stream>>>(offsets, csr_src, el1,
                                                      er1, m1, d1);
  agg1_kernel<<<N_NODES, 256, 0, stream>>>(offsets, csr_src, el1, er1, m1, d1,
                                           f1, b1, h1);

  // --- layer 2 ---
  gemm_mfma<256, 2, 1><<<196, 256, 0, stream>>>(h1, b2hi, b2lo, f2, N_NODES);
  elr2_kernel<<<(N_NODES + 3) / 4, 256, 0, stream>>>(f2, al2, ar2, el2, er2);
  mden2_kernel<<<(N_NODES + 3) / 4, 256, 0, stream>>>(offsets, csr_src, el2,
                                                      er2, m2, d2);
  agg2_kernel<<<(N_NODES + 3) / 4, 256, 0, stream>>>(offsets, csr_src, el2, er2,
                                                     m2, d2, f2, b2, out);
}

// Round 5
// 541.385 us; speedup vs baseline: 1.5834x; 1.0831x over previous
//
#include <hip/hip_runtime.h>

#define N_NODES 50000
#define N_EDGES 800000
#define IN_DIM 512
#define NEG_SLOPE 0.2f

typedef short short8 __attribute__((ext_vector_type(8)));
typedef float f32x16 __attribute__((ext_vector_type(16)));

// ---------------- bf16 split helpers (RNE) ----------------
__device__ __forceinline__ unsigned bf16rne(float f) {
  union { float f; unsigned u; } v;
  v.f = f;
  return (v.u + 0x7FFFu + ((v.u >> 16) & 1u)) >> 16;
}
__device__ __forceinline__ float bf16tof(unsigned b) {
  union { unsigned u; float f; } v;
  v.u = b << 16;
  return v.f;
}
__device__ __forceinline__ void split8(float4 a, float4 b, short8& hi,
                                       short8& lo) {
  float v[8] = {a.x, a.y, a.z, a.w, b.x, b.y, b.z, b.w};
#pragma unroll
  for (int i = 0; i < 8; i++) {
    unsigned h = bf16rne(v[i]);
    hi[i] = (short)h;
    lo[i] = (short)bf16rne(v[i] - bf16tof(h));
  }
}

// ---------------- W pre-pack into MFMA B-fragment order ----------------
__global__ void pack_w(const float* __restrict__ W, short* __restrict__ Bhi,
                       short* __restrict__ Blo, int N) {
  int k = blockIdx.x, n = threadIdx.x;
  float w = W[(size_t)k * N + n];
  unsigned h = bf16rne(w);
  unsigned l = bf16rne(w - bf16tof(h));
  int ksub = k >> 4, kh = (k >> 3) & 1, j = k & 7;
  int nsub = n >> 5, lane2 = (n & 31) | (kh << 5);
  size_t off = (((size_t)ksub * (N >> 5) + nsub) * 64 + lane2) * 8 + j;
  Bhi[off] = (short)h;
  Blo[off] = (short)l;
}

// ---------------- split-bf16 MFMA GEMM, barrier-free ----------------
// Optional Cb: bf16 copy of C (for downstream gather kernels).
template <int K, int NSUBS, int NTILES>
__global__ __launch_bounds__(256) void gemm_mfma(const float* __restrict__ A,
                                                 const short* __restrict__ Bhi_,
                                                 const short* __restrict__ Blo_,
                                                 float* __restrict__ C,
                                                 unsigned short* __restrict__ Cb,
                                                 int M) {
  const int N = NSUBS * 32;
  int lane = threadIdx.x & 63;
  int wid = blockIdx.x * 4 + (threadIdx.x >> 6);
  int mtiles = (M + 63) >> 6;
  int mtile = wid / NTILES, ntile = wid % NTILES;
  if (mtile >= mtiles) return;
  int half = lane >> 5, l31 = lane & 31;
  int m0 = mtile * 64;
  int r0 = min(m0 + l31, M - 1);
  int r1 = min(m0 + 32 + l31, M - 1);
  const float* a0p = A + (size_t)r0 * K + half * 8;
  const float* a1p = A + (size_t)r1 * K + half * 8;
  const short8* bh = (const short8*)Bhi_;
  const short8* bl = (const short8*)Blo_;
  size_t bidx = (size_t)(ntile * 2) * 64 + lane;
  f32x16 acc00 = {}, acc01 = {}, acc10 = {}, acc11 = {};
#pragma unroll 2
  for (int ks = 0; ks < K / 16; ks++) {
    float4 x0 = *(const float4*)(a0p + ks * 16);
    float4 x1 = *(const float4*)(a0p + ks * 16 + 4);
    float4 y0 = *(const float4*)(a1p + ks * 16);
    float4 y1 = *(const float4*)(a1p + ks * 16 + 4);
    short8 a0h, a0l, a1h, a1l;
    split8(x0, x1, a0h, a0l);
    split8(y0, y1, a1h, a1l);
    size_t bb = bidx + (size_t)ks * NSUBS * 64;
    short8 b0h = bh[bb], b0l = bl[bb];
    short8 b1h = bh[bb + 64], b1l = bl[bb + 64];
    acc00 = __builtin_amdgcn_mfma_f32_32x32x16_bf16(a0h, b0h, acc00, 0, 0, 0);
    acc00 = __builtin_amdgcn_mfma_f32_32x32x16_bf16(a0h, b0l, acc00, 0, 0, 0);
    acc00 = __builtin_amdgcn_mfma_f32_32x32x16_bf16(a0l, b0h, acc00, 0, 0, 0);
    acc01 = __builtin_amdgcn_mfma_f32_32x32x16_bf16(a0h, b1h, acc01, 0, 0, 0);
    acc01 = __builtin_amdgcn_mfma_f32_32x32x16_bf16(a0h, b1l, acc01, 0, 0, 0);
    acc01 = __builtin_amdgcn_mfma_f32_32x32x16_bf16(a0l, b1h, acc01, 0, 0, 0);
    acc10 = __builtin_amdgcn_mfma_f32_32x32x16_bf16(a1h, b0h, acc10, 0, 0, 0);
    acc10 = __builtin_amdgcn_mfma_f32_32x32x16_bf16(a1h, b0l, acc10, 0, 0, 0);
    acc10 = __builtin_amdgcn_mfma_f32_32x32x16_bf16(a1l, b0h, acc10, 0, 0, 0);
    acc11 = __builtin_amdgcn_mfma_f32_32x32x16_bf16(a1h, b1h, acc11, 0, 0, 0);
    acc11 = __builtin_amdgcn_mfma_f32_32x32x16_bf16(a1h, b1l, acc11, 0, 0, 0);
    acc11 = __builtin_amdgcn_mfma_f32_32x32x16_bf16(a1l, b1h, acc11, 0, 0, 0);
  }
  int colbase = ntile * 64 + l31;
#pragma unroll
  for (int r = 0; r < 16; r++) {
    int roff = (r & 3) + 8 * (r >> 2) + 4 * half;
    int row = m0 + roff;
    if (row < M) {
      C[(size_t)row * N + colbase] = acc00[r];
      C[(size_t)row * N + colbase + 32] = acc01[r];
      if (Cb) {
        Cb[(size_t)row * N + colbase] = (unsigned short)bf16rne(acc00[r]);
        Cb[(size_t)row * N + colbase + 32] = (unsigned short)bf16rne(acc01[r]);
      }
    }
    if (row + 32 < M) {
      C[(size_t)(row + 32) * N + colbase] = acc10[r];
      C[(size_t)(row + 32) * N + colbase + 32] = acc11[r];
      if (Cb) {
        Cb[(size_t)(row + 32) * N + colbase] =
            (unsigned short)bf16rne(acc10[r]);
        Cb[(size_t)(row + 32) * N + colbase + 32] =
            (unsigned short)bf16rne(acc11[r]);
      }
    }
  }
}

// ---------------- el/er reductions ----------------
__global__ __launch_bounds__(256) void elr1_kernel(
    const float* __restrict__ f1, const float* __restrict__ al,
    const float* __restrict__ ar, float* __restrict__ el,
    float* __restrict__ er) {
  int n = blockIdx.x;
  int t = threadIdx.x;
  int h = t >> 6, lane = t & 63;
  float v = f1[(size_t)n * 256 + t];
  float a = v * al[t];
  float b = v * ar[t];
  for (int off = 32; off; off >>= 1) {
    a += __shfl_down(a, off);
    b += __shfl_down(b, off);
  }
  if (lane == 0) {
    el[n * 4 + h] = a;
    er[n * 4 + h] = b;
  }
}

__global__ __launch_bounds__(256) void elr2_kernel(
    const float* __restrict__ f2, const float* __restrict__ al,
    const float* __restrict__ ar, float* __restrict__ el,
    float* __restrict__ er) {
  int w = threadIdx.x >> 6, lane = threadIdx.x & 63;
  int n = blockIdx.x * 4 + w;
  if (n >= N_NODES) return;
  float v = f2[(size_t)n * 64 + lane];
  float a = v * al[lane], b = v * ar[lane];
  for (int off = 32; off; off >>= 1) {
    a += __shfl_down(a, off);
    b += __shfl_down(b, off);
  }
  if (lane == 0) {
    el[n] = a;
    er[n] = b;
  }
}

// ---------------- CSR build ----------------
__global__ void hist_kernel(const int* __restrict__ dst,
                            int* __restrict__ counts) {
  int e = blockIdx.x * blockDim.x + threadIdx.x;
  if (e < N_EDGES) atomicAdd(&counts[dst[e]], 1);
}

#define NSCAN 196  // ceil(50000/256)
__global__ __launch_bounds__(256) void scan_part(const int* __restrict__ counts,
                                                 int* __restrict__ offsets,
                                                 int* __restrict__ bsums) {
  __shared__ int sh[256];
  int t = threadIdx.x;
  int i = blockIdx.x * 256 + t;
  int v = (i < N_NODES) ? counts[i] : 0;
  sh[t] = v;
  __syncthreads();
  for (int o = 1; o < 256; o <<= 1) {
    int x = (t >= o) ? sh[t - o] : 0;
    __syncthreads();
    sh[t] += x;
    __syncthreads();
  }
  if (i < N_NODES) offsets[i] = sh[t] - v;
  if (t == 255) bsums[blockIdx.x] = sh[255];
}
__global__ __launch_bounds__(256) void scan_top(int* __restrict__ bsums) {
  __shared__ int sh[256];
  int t = threadIdx.x;
  int v = (t < NSCAN) ? bsums[t] : 0;
  sh[t] = v;
  __syncthreads();
  for (int o = 1; o < 256; o <<= 1) {
    int x = (t >= o) ? sh[t - o] : 0;
    __syncthreads();
    sh[t] += x;
    __syncthreads();
  }
  if (t < NSCAN) bsums[t] = sh[t] - v;
}
__global__ __launch_bounds__(256) void scan_add(int* __restrict__ offsets,
                                                const int* __restrict__ bsums) {
  int i = blockIdx.x * 256 + threadIdx.x;
  if (i < N_NODES) offsets[i] += bsums[blockIdx.x];
  if (i == 0) offsets[N_NODES] = N_EDGES;
}

__global__ void scatter_kernel(const int* __restrict__ src,
                               const int* __restrict__ dst,
                               const int* __restrict__ offsets,
                               int* __restrict__ fill,
                               int* __restrict__ csr_src) {
  int e = blockIdx.x * blockDim.x + threadIdx.x;
  if (e < N_EDGES) {
    int d = dst[e];
    int pos = offsets[d] + atomicAdd(&fill[d], 1);
    csr_src[pos] = src[e];
  }
}

// ---------------- softmax max/denominator (online) ----------------
__global__ __launch_bounds__(256) void mden1_kernel(
    const int* __restrict__ offsets, const int* __restrict__ csr_src,
    const float* __restrict__ el, const float* __restrict__ er,
    float* __restrict__ mout, float* __restrict__ dout) {
  int w = threadIdx.x >> 6, lane = threadIdx.x & 63;
  int n = blockIdx.x * 4 + w;
  if (n >= N_NODES) return;
  int off0 = offsets[n], deg = offsets[n + 1] - off0;
  float4 erv = ((const float4*)er)[n];
  float er4[4] = {erv.x, erv.y, erv.z, erv.w};
  float m[4] = {-1e30f, -1e30f, -1e30f, -1e30f};
  float l[4] = {0.f, 0.f, 0.f, 0.f};
  for (int i = lane; i < deg; i += 64) {
    int s = csr_src[off0 + i];
    float4 elv = ((const float4*)el)[s];
    float e4[4] = {elv.x, elv.y, elv.z, elv.w};
#pragma unroll
    for (int h = 0; h < 4; h++) {
      float v = e4[h] + er4[h];
      v = v > 0.f ? v : NEG_SLOPE * v;
      float nm = fmaxf(m[h], v);
      l[h] = l[h] * __expf(m[h] - nm) + __expf(v - nm);
      m[h] = nm;
    }
  }
  for (int d = 32; d; d >>= 1) {
#pragma unroll
    for (int h = 0; h < 4; h++) {
      float mo = __shfl_down(m[h], d);
      float lo = __shfl_down(l[h], d);
      float nm = fmaxf(m[h], mo);
      l[h] = l[h] * __expf(m[h] - nm) + lo * __expf(mo - nm);
      m[h] = nm;
    }
  }
  if (lane == 0) {
#pragma unroll
    for (int h = 0; h < 4; h++) {
      mout[n * 4 + h] = m[h];
      dout[n * 4 + h] = l[h];
    }
  }
}

__global__ __launch_bounds__(256) void mden2_kernel(
    const int* __restrict__ offsets, const int* __restrict__ csr_src,
    const float* __restrict__ el, const float* __restrict__ er,
    float* __restrict__ mout, float* __restrict__ dout) {
  int w = threadIdx.x >> 6, lane = threadIdx.x & 63;
  int n = blockIdx.x * 4 + w;
  if (n >= N_NODES) return;
  int off0 = offsets[n], deg = offsets[n + 1] - off0;
  float ern = er[n];
  float m = -1e30f, l = 0.f;
  for (int i = lane; i < deg; i += 64) {
    int s = csr_src[off0 + i];
    float v = el[s] + ern;
    v = v > 0.f ? v : NEG_SLOPE * v;
    float nm = fmaxf(m, v);
    l = l * __expf(m - nm) + __expf(v - nm);
    m = nm;
  }
  for (int d = 32; d; d >>= 1) {
    float mo = __shfl_down(m, d);
    float lo = __shfl_down(l, d);
    float nm = fmaxf(m, mo);
    l = l * __expf(m - nm) + lo * __expf(mo - nm);
    m = nm;
  }
  if (lane == 0) {
    mout[n] = m;
    dout[n] = l;
  }
}

// ---------------- aggregation layer 1: bf16 gather, 2x unroll ----------------
__global__ __launch_bounds__(256) void agg1_kernel(
    const int* __restrict__ offsets, const int* __restrict__ csr_src,
    const float* __restrict__ el, const float* __restrict__ er,
    const float* __restrict__ mm, const float* __restrict__ den,
    const unsigned short* __restrict__ fb, const float* __restrict__ bias,
    float* __restrict__ h1) {
  __shared__ float red[3][256];
  int n = blockIdx.x;
  int t = threadIdx.x;
  int w = t >> 6, lane = t & 63;
  int h = lane >> 4;
  int off0 = offsets[n], deg = offsets[n + 1] - off0;
  float erh = er[n * 4 + h];
  float mh = mm[n * 4 + h];
  float invd = 1.0f / den[n * 4 + h];
  float4 acc = {0.f, 0.f, 0.f, 0.f};
  float4 acc2 = {0.f, 0.f, 0.f, 0.f};
  int i = w;
  for (; i + 4 < deg; i += 8) {
    int s0 = csr_src[off0 + i];
    int s1 = csr_src[off0 + i + 4];
    float e0 = el[s0 * 4 + h] + erh;
    float e1 = el[s1 * 4 + h] + erh;
    e0 = e0 > 0.f ? e0 : NEG_SLOPE * e0;
    e1 = e1 > 0.f ? e1 : NEG_SLOPE * e1;
    float a0 = __expf(e0 - mh) * invd;
    float a1 = __expf(e1 - mh) * invd;
    uint2 p0 = *(const uint2*)(fb + (size_t)s0 * 256 + lane * 4);
    uint2 p1 = *(const uint2*)(fb + (size_t)s1 * 256 + lane * 4);
    acc.x += a0 * __uint_as_float(p0.x << 16);
    acc.y += a0 * __uint_as_float(p0.x & 0xffff0000u);
    acc.z += a0 * __uint_as_float(p0.y << 16);
    acc.w += a0 * __uint_as_float(p0.y & 0xffff0000u);
    acc2.x += a1 * __uint_as_float(p1.x << 16);
    acc2.y += a1 * __uint_as_float(p1.x & 0xffff0000u);
    acc2.z += a1 * __uint_as_float(p1.y << 16);
    acc2.w += a1 * __uint_as_float(p1.y & 0xffff0000u);
  }
  if (i < deg) {
    int s0 = csr_src[off0 + i];
    float e0 = el[s0 * 4 + h] + erh;
    e0 = e0 > 0.f ? e0 : NEG_SLOPE * e0;
    float a0 = __expf(e0 - mh) * invd;
    uint2 p0 = *(const uint2*)(fb + (size_t)s0 * 256 + lane * 4);
    acc.x += a0 * __uint_as_float(p0.x << 16);
    acc.y += a0 * __uint_as_float(p0.x & 0xffff0000u);
    acc.z += a0 * __uint_as_float(p0.y << 16);
    acc.w += a0 * __uint_as_float(p0.y & 0xffff0000u);
  }
  acc.x += acc2.x;
  acc.y += acc2.y;
  acc.z += acc2.z;
  acc.w += acc2.w;
  if (w) *(float4*)(&red[w - 1][lane * 4]) = acc;
  __syncthreads();
  if (w == 0) {
    float4 r0 = *(float4*)(&red[0][lane * 4]);
    float4 r1 = *(float4*)(&red[1][lane * 4]);
    float4 r2 = *(float4*)(&red[2][lane * 4]);
    float4 b = ((const float4*)bias)[lane];
    float o[4] = {acc.x + r0.x + r1.x + r2.x + b.x,
                  acc.y + r0.y + r1.y + r2.y + b.y,
                  acc.z + r0.z + r1.z + r2.z + b.z,
                  acc.w + r0.w + r1.w + r2.w + b.w};
#pragma unroll
    for (int j = 0; j < 4; j++) o[j] = o[j] > 0.f ? o[j] : __expf(o[j]) - 1.0f;
    float4 ov = {o[0], o[1], o[2], o[3]};
    *(float4*)(h1 + (size_t)n * 256 + lane * 4) = ov;
  }
}

// ---------------- aggregation layer 2 (fp32, unchanged) ----------------
__global__ __launch_bounds__(256) void agg2_kernel(
    const int* __restrict__ offsets, const int* __restrict__ csr_src,
    const float* __restrict__ el, const float* __restrict__ er,
    const float* __restrict__ mm, const float* __restrict__ den,
    const float* __restrict__ f2, const float* __restrict__ bias,
    float* __restrict__ out) {
  int w = threadIdx.x >> 6, lane = threadIdx.x & 63;
  int n = blockIdx.x * 4 + w;
  if (n >= N_NODES) return;
  int dg = lane & 15, eslot = lane >> 4;
  int off0 = offsets[n], deg = offsets[n + 1] - off0;
  float ern = er[n], mn = mm[n];
  float invd = 1.0f / den[n];
  float4 acc = {0.f, 0.f, 0.f, 0.f};
  for (int i = eslot; i < deg; i += 4) {
    int s = csr_src[off0 + i];
    float e = el[s] + ern;
    e = e > 0.f ? e : NEG_SLOPE * e;
    float a = __expf(e - mn) * invd;
    float4 v = *(const float4*)(f2 + (size_t)s * 64 + dg * 4);
    acc.x += a * v.x;
    acc.y += a * v.y;
    acc.z += a * v.z;
    acc.w += a * v.w;
  }
#pragma unroll
  for (int off = 16; off < 64; off <<= 1) {
    acc.x += __shfl_xor(acc.x, off);
    acc.y += __shfl_xor(acc.y, off);
    acc.z += __shfl_xor(acc.z, off);
    acc.w += __shfl_xor(acc.w, off);
  }
  if (eslot == 0) {
    float4 b = ((const float4*)bias)[dg];
    float4 ov = {acc.x + b.x, acc.y + b.y, acc.z + b.z, acc.w + b.w};
    *(float4*)(out + (size_t)n * 64 + dg * 4) = ov;
  }
}

extern "C" void kernel_launch(void* const* d_in, const int* in_sizes, int n_in,
                              void* d_out, int out_size, void* d_ws,
                              size_t ws_size, hipStream_t stream) {
  const float* features = (const float*)d_in[0];
  const float* W1 = (const float*)d_in[1];
  const float* al1 = (const float*)d_in[2];
  const float* ar1 = (const float*)d_in[3];
  const float* b1 = (const float*)d_in[4];
  const float* W2 = (const float*)d_in[5];
  const float* al2 = (const float*)d_in[6];
  const float* ar2 = (const float*)d_in[7];
  const float* b2 = (const float*)d_in[8];
  const int* src = (const int*)d_in[9];
  const int* dst = (const int*)d_in[10];
  float* out = (float*)d_out;

  // Workspace aliasing (lifetime-checked):
  //  region A (51.2 MB): f1 fp32 (gemm1 out) -> dead after elr1 -> h1 (agg1
  //  out) -> read by gemm2.
  //  region B (25.6 MB): fb bf16(f1) (gemm1 out) -> dead after agg1 -> f2
  //  (gemm2 out, 12.8 MB) -> read by elr2/mden2(el)/agg2.
  float* f1 = (float*)d_ws;                       // region A
  float* h1 = f1;                                 // region A (reuse)
  unsigned short* fb =
      (unsigned short*)(f1 + (size_t)N_NODES * 256);  // region B
  float* f2 = (float*)fb;                             // region B (reuse)
  float* el1 = f1 + (size_t)N_NODES * 256 + (size_t)N_NODES * 128;  // after B
  float* er1 = el1 + N_NODES * 4;
  float* m1 = er1 + N_NODES * 4;
  float* d1 = m1 + N_NODES * 4;
  float* el2 = d1 + N_NODES * 4;
  float* er2 = el2 + N_NODES;
  float* m2 = er2 + N_NODES;
  float* d2 = m2 + N_NODES;
  int* counts = (int*)(d2 + N_NODES);
  int* offsets = counts + N_NODES;
  int* fill = offsets + N_NODES + 1;
  int* csr_src = fill + N_NODES;
  int* bsums = csr_src + N_EDGES;

  // B-pack scratch: b1 packs in d_out (dead until agg2); b2 packs in `fill`
  // (dead after scatter).
  short* b1hi = (short*)d_out;
  short* b1lo = b1hi + 512 * 256;
  short* b2hi = (short*)fill;
  short* b2lo = b2hi + 256 * 64;

  // --- CSR build ---
  hipMemsetAsync(counts, 0, N_NODES * sizeof(int), stream);
  hipMemsetAsync(fill, 0, N_NODES * sizeof(int), stream);
  hist_kernel<<<(N_EDGES + 255) / 256, 256, 0, stream>>>(dst, counts);
  scan_part<<<NSCAN, 256, 0, stream>>>(counts, offsets, bsums);
  scan_top<<<1, 256, 0, stream>>>(bsums);
  scan_add<<<NSCAN, 256, 0, stream>>>(offsets, bsums);
  scatter_kernel<<<(N_EDGES + 255) / 256, 256, 0, stream>>>(src, dst, offsets,
                                                            fill, csr_src);

  // --- weight packing ---
  pack_w<<<512, 256, 0, stream>>>(W1, b1hi, b1lo, 256);
  pack_w<<<256, 64, 0, stream>>>(W2, b2hi, b2lo, 64);

  // --- layer 1 ---
  gemm_mfma<IN_DIM, 8, 4><<<782, 256, 0, stream>>>(features, b1hi, b1lo, f1, fb,
                                                   N_NODES);
  elr1_kernel<<<N_NODES, 256, 0, stream>>>(f1, al1, ar1, el1, er1);
  mden1_kernel<<<(N_NODES + 3) / 4, 256, 0, stream>>>(offsets, csr_src, el1,
                                                      er1, m1, d1);
  agg1_kernel<<<N_NODES, 256, 0, stream>>>(offsets, csr_src, el1, er1, m1, d1,
                                           fb, b1, h1);

  // --- layer 2 ---
  gemm_mfma<256, 2, 1><<<196, 256, 0, stream>>>(h1, b2hi, b2lo, f2,
                                                (unsigned short*)nullptr,
                                                N_NODES);
  elr2_kernel<<<(N_NODES + 3) / 4, 256, 0, stream>>>(f2, al2, ar2, el2, er2);
  mden2_kernel<<<(N_NODES + 3) / 4, 256, 0, stream>>>(offsets, csr_src, el2,
                                                      er2, m2, d2);
  agg2_kernel<<<(N_NODES + 3) / 4, 256, 0, stream>>>(offsets, csr_src, el2, er2,
                                                     m2, d2, f2, b2, out);
}